// Round 5
// baseline (4145.530 us; speedup 1.0000x reference)
//
#include <hip/hip_runtime.h>

#define NN 262144   // rows (embeddings)
#define DD 128      // dim
#define KK 512      // clusters
#define NITER 5

// workspace layout
#define WS_A16_BYTES   (NN * 2)                       // u16 assigns
#define WS_SUMS_OFF    (WS_A16_BYTES)                 // 2048 x 128 f32 partials
#define WS_CNTS_OFF    (WS_SUMS_OFF + 2048 * DD * 4)  // 2048 i32 counts
#define WS_CTG_OFF     (WS_CNTS_OFF + 2048 * 4)       // C^T [128 d][512 k] f32
#define WS_NEEDED      (WS_CTG_OFF + DD * KK * 4)

#define GLOAD_LDS16(gp, lp)                                                     \
    __builtin_amdgcn_global_load_lds(                                           \
        (const __attribute__((address_space(1))) void*)(gp),                    \
        (__attribute__((address_space(3))) void*)(lp), 16, 0, 0)

// ---------------------------------------------------------------------------
// C transpose: CTg[d][k] = C[k][d]  (256 KB, coalesced writes)
// ---------------------------------------------------------------------------
__global__ __launch_bounds__(256) void transpose_c_kernel(
    const float* __restrict__ C, float* __restrict__ CTg)
{
    int flat = blockIdx.x * 256 + threadIdx.x;   // 65536 total
    int d = flat >> 9, k = flat & 511;
    CTg[flat] = C[k * DD + d];
}

// ---------------------------------------------------------------------------
// Kernel A (fast): 128 rows x 512 k per block, k-chunks of 256, d-phases of 16.
// ALL staging via global_load_lds DMA (no staging VALU, no ds_writes):
//   ET [128 r][16 d] row-major  (8 KB)  <- gather DMA straight from E
//   CT [16 d][256 k] d-major    (16 KB) <- coalesced DMA from CTg
// Compute: per 4-d group, A = b128 (1 row x 4 d, broadcast across tx),
// B = b128 (4 contiguous k at one d, uniform bank coverage). Argmax merged
// with 5-round __shfl_xor per row (no LDS scratch).
// ---------------------------------------------------------------------------
__global__ __launch_bounds__(256, 2) void assign_kernel(
    const float* __restrict__ E, const float* __restrict__ CTg,
    int* __restrict__ assignv, unsigned short* __restrict__ assign16)
{
    __shared__ float ET[128 * 16];   // [r][d], stride 16 (DMA-contiguous)
    __shared__ float CT[16 * 256];   // [d][k], stride 256

    const int tid  = threadIdx.x;
    const int tx   = tid & 31;
    const int ty   = tid >> 5;        // 0..7 -> rows ty*16..+15
    const int w    = tid >> 6;
    const int lane = tid & 63;
    const int r0   = blockIdx.x * 128;

    float bbv = 0.f;   // running best (valid in tx<16 writer threads)
    int   bbk = 0;

    for (int chunk = 0; chunk < 2; ++chunk) {
        const int k0 = chunk * 256;
        float acc[16][8];
#pragma unroll
        for (int i = 0; i < 16; ++i)
#pragma unroll
            for (int j = 0; j < 8; ++j) acc[i][j] = 0.f;

        for (int ph = 0; ph < 8; ++ph) {
            const int d0 = ph * 16;
            __syncthreads();   // previous phase's readers done
            // E tile DMA: instr t covers rows t*16..+15, d0..d0+15.
            // lane L -> row t*16 + (L>>2), bytes (L&3)*16 of that row's 64-B
            // d-span; LDS dst = base + L*16 (row-major stride 16 floats).
#pragma unroll
            for (int q = 0; q < 2; ++q) {
                int t = w * 2 + q;
                const float* gp = E + (size_t)(r0 + t * 16 + (lane >> 2)) * DD
                                    + d0 + (lane & 3) * 4;
                GLOAD_LDS16(gp, ET + t * 256);
            }
            // C tile DMA: instr dd = one d-row of CTg, cols k0..k0+255
            // (fully coalesced; lane L -> floats k0+4L..+3).
#pragma unroll
            for (int q = 0; q < 4; ++q) {
                int dd = w * 4 + q;
                const float* gp = CTg + (size_t)(d0 + dd) * KK + k0 + lane * 4;
                GLOAD_LDS16(gp, CT + dd * 256);
            }
            __syncthreads();   // drains vmcnt -> DMA complete

#pragma unroll
            for (int dg = 0; dg < 4; ++dg) {      // 4-d groups
                float4 b0[4], b1[4];
#pragma unroll
                for (int c = 0; c < 4; ++c) {
                    b0[c] = *(const float4*)&CT[(dg * 4 + c) * 256 + tx * 4];
                    b1[c] = *(const float4*)&CT[(dg * 4 + c) * 256 + 128 + tx * 4];
                }
#pragma unroll
                for (int rq = 0; rq < 4; ++rq) {
                    float4 a[4];
#pragma unroll
                    for (int rr = 0; rr < 4; ++rr)
                        a[rr] = *(const float4*)&ET[(ty * 16 + rq * 4 + rr) * 16 + dg * 4];
#pragma unroll
                    for (int c = 0; c < 4; ++c) {
#pragma unroll
                        for (int rr = 0; rr < 4; ++rr) {
                            const int i = rq * 4 + rr;
                            const float av = (c == 0) ? a[rr].x : (c == 1) ? a[rr].y
                                           : (c == 2) ? a[rr].z : a[rr].w;
                            acc[i][0] = fmaf(av, b0[c].x, acc[i][0]);
                            acc[i][1] = fmaf(av, b0[c].y, acc[i][1]);
                            acc[i][2] = fmaf(av, b0[c].z, acc[i][2]);
                            acc[i][3] = fmaf(av, b0[c].w, acc[i][3]);
                            acc[i][4] = fmaf(av, b1[c].x, acc[i][4]);
                            acc[i][5] = fmaf(av, b1[c].y, acc[i][5]);
                            acc[i][6] = fmaf(av, b1[c].z, acc[i][6]);
                            acc[i][7] = fmaf(av, b1[c].w, acc[i][7]);
                        }
                    }
                }
            }
        }

        // Argmax. Thread's 8 cols: j<4 -> k0+4tx+j (ascending), j>=4 ->
        // k0+128+4tx+(j-4) (ascending) => strict > is first-occurrence
        // correct within the thread. Cross-tx candidates interleave, so the
        // shuffle merge breaks ties on lower global index. Candidates for
        // row ty*16+i live in the 32-lane half sharing ty (xor masks <=16
        // stay inside a half).
#pragma unroll
        for (int i = 0; i < 16; ++i) {
            float v = acc[i][0]; int bj = 0;
#pragma unroll
            for (int j = 1; j < 8; ++j)
                if (acc[i][j] > v) { v = acc[i][j]; bj = j; }
            int gk = k0 + ((bj < 4) ? (tx * 4 + bj) : (128 + tx * 4 + (bj - 4)));
#pragma unroll
            for (int m = 1; m <= 16; m <<= 1) {
                float ov = __shfl_xor(v, m, 64);
                int   og = __shfl_xor(gk, m, 64);
                if (ov > v || (ov == v && og < gk)) { v = ov; gk = og; }
            }
            if (tx == i) {   // writer thread for row ty*16+i
                if (chunk == 0 || v > bbv) { bbv = v; bbk = gk; }
                // tie across chunks: chunk-0 index is always lower -> keep it
            }
        }
    }
    if (tx < 16) {
        int row = r0 + ty * 16 + tx;
        assignv[row]  = bbk;
        assign16[row] = (unsigned short)bbk;
    }
}

// ---------------------------------------------------------------------------
// Fast M-step, phase 1: 2048 blocks = 4 per cluster (verified in r4).
// ---------------------------------------------------------------------------
__global__ __launch_bounds__(256) void update_partial_kernel(
    const float* __restrict__ E, const unsigned short* __restrict__ assign16,
    float* __restrict__ ws_sums, int* __restrict__ ws_cnts)
{
    const int b   = blockIdx.x;
    const int k   = b >> 2;
    const int qtr = b & 3;

    __shared__ float acc[4][DD];
    __shared__ int   cnts[4];

    const int tid  = threadIdx.x;
    const int w    = tid >> 6;
    const int lane = tid & 63;

    float a0 = 0.f, a1 = 0.f;
    int cnt = 0;
    const int wbase = qtr * (NN / 4) + w * (NN / 16);

    for (int it = 0; it < (NN / 16) / 512; ++it) {
        const int off = wbase + it * 512;
        uint4 p = *(const uint4*)&assign16[off + lane * 8];
        unsigned v[4] = {p.x, p.y, p.z, p.w};
#pragma unroll
        for (int h = 0; h < 4; ++h) {
            int lo = (int)(v[h] & 0xffffu);
            int hi = (int)(v[h] >> 16);
            unsigned long long mlo = __ballot(lo == k);
            unsigned long long mhi = __ballot(hi == k);
            cnt += (int)__popcll(mlo) + (int)__popcll(mhi);
            while (mlo) {
                int b2 = __ffsll((long long)mlo) - 1; mlo &= mlo - 1;
                int row = off + b2 * 8 + h * 2;
                float2 e = *(const float2*)&E[(size_t)row * DD + lane * 2];
                a0 += e.x; a1 += e.y;
            }
            while (mhi) {
                int b2 = __ffsll((long long)mhi) - 1; mhi &= mhi - 1;
                int row = off + b2 * 8 + h * 2 + 1;
                float2 e = *(const float2*)&E[(size_t)row * DD + lane * 2];
                a0 += e.x; a1 += e.y;
            }
        }
    }
    acc[w][lane * 2]     = a0;
    acc[w][lane * 2 + 1] = a1;
    if (lane == 0) cnts[w] = cnt;
    __syncthreads();
    if (tid < DD)
        ws_sums[(size_t)b * DD + tid] = acc[0][tid] + acc[1][tid] + acc[2][tid] + acc[3][tid];
    if (tid == 0)
        ws_cnts[b] = cnts[0] + cnts[1] + cnts[2] + cnts[3];
}

__global__ __launch_bounds__(128) void update_combine_kernel(
    const float* __restrict__ ws_sums, const int* __restrict__ ws_cnts,
    float* __restrict__ C)
{
    const int k = blockIdx.x, t = threadIdx.x;
    __shared__ float red[2];
    const int w = t >> 6, lane = t & 63;

    float s = ws_sums[(size_t)(4 * k + 0) * DD + t]
            + ws_sums[(size_t)(4 * k + 1) * DD + t]
            + ws_sums[(size_t)(4 * k + 2) * DD + t]
            + ws_sums[(size_t)(4 * k + 3) * DD + t];
    int cnt = ws_cnts[4 * k] + ws_cnts[4 * k + 1] + ws_cnts[4 * k + 2] + ws_cnts[4 * k + 3];
    float m = (cnt > 0) ? s / (float)cnt : C[k * DD + t];

    float sq = m * m;
#pragma unroll
    for (int o = 32; o > 0; o >>= 1) sq += __shfl_down(sq, o, 64);
    if (lane == 0) red[w] = sq;
    __syncthreads();
    float nrm = fmaxf(sqrtf(red[0] + red[1]), 1e-12f);
    C[k * DD + t] = m / nrm;
}

// ---------------------------------------------------------------------------
// Fallback path (ws too small): r4's verified assign + r1's update.
// ---------------------------------------------------------------------------
#define SE 132
#define SC 260
#define SS 129
__global__ __launch_bounds__(256, 2) void assign_kernel_fb(
    const float* __restrict__ E, const float* __restrict__ C,
    int* __restrict__ assignv)
{
    __shared__ float smem[32 * SE + 32 * SC];
    float* ET = smem;
    float* CT = smem + 32 * SE;
    float* sval = smem;
    int*   sidx = ((int*)smem) + 32 * SS;

    const int tid = threadIdx.x;
    const int tx  = tid & 31;
    const int ty  = tid >> 5;
    const int r0  = blockIdx.x * 128;

    float bbv = 0.f; int bbk = 0;

    for (int chunk = 0; chunk < 2; ++chunk) {
        const int k0 = chunk * 256;
        float acc[16][8];
#pragma unroll
        for (int i = 0; i < 16; ++i)
#pragma unroll
            for (int j = 0; j < 8; ++j) acc[i][j] = 0.f;

        for (int sub = 0; sub < 4; ++sub) {
            const int d0 = sub * 32;
            __syncthreads();
#pragma unroll
            for (int it = 0; it < 4; ++it) {
                int idx = tid + it * 256;
                int r = idx >> 3, q = idx & 7;
                float4 v = *(const float4*)&E[(r0 + r) * DD + d0 + q * 4];
                ET[(q * 4 + 0) * SE + r] = v.x;
                ET[(q * 4 + 1) * SE + r] = v.y;
                ET[(q * 4 + 2) * SE + r] = v.z;
                ET[(q * 4 + 3) * SE + r] = v.w;
            }
#pragma unroll
            for (int it = 0; it < 8; ++it) {
                int idx = tid + it * 256;
                int k = idx >> 3, q = idx & 7;
                float4 v = *(const float4*)&C[(k0 + k) * DD + d0 + q * 4];
                CT[(q * 4 + 0) * SC + k] = v.x;
                CT[(q * 4 + 1) * SC + k] = v.y;
                CT[(q * 4 + 2) * SC + k] = v.z;
                CT[(q * 4 + 3) * SC + k] = v.w;
            }
            __syncthreads();
#pragma unroll 4
            for (int d = 0; d < 32; ++d) {
                float4 a0 = *(const float4*)&ET[d * SE + ty * 16];
                float4 a1 = *(const float4*)&ET[d * SE + ty * 16 + 4];
                float4 a2 = *(const float4*)&ET[d * SE + ty * 16 + 8];
                float4 a3 = *(const float4*)&ET[d * SE + ty * 16 + 12];
                float4 b0 = *(const float4*)&CT[d * SC + tx * 4];
                float4 b1 = *(const float4*)&CT[d * SC + 128 + tx * 4];
                float ra[16] = {a0.x, a0.y, a0.z, a0.w, a1.x, a1.y, a1.z, a1.w,
                                a2.x, a2.y, a2.z, a2.w, a3.x, a3.y, a3.z, a3.w};
                float rb[8]  = {b0.x, b0.y, b0.z, b0.w, b1.x, b1.y, b1.z, b1.w};
#pragma unroll
                for (int i = 0; i < 16; ++i)
#pragma unroll
                    for (int j = 0; j < 8; ++j)
                        acc[i][j] = fmaf(ra[i], rb[j], acc[i][j]);
            }
        }
        __syncthreads();
#pragma unroll
        for (int i = 0; i < 16; ++i) {
            float bv = acc[i][0]; int bj = 0;
#pragma unroll
            for (int j = 1; j < 8; ++j)
                if (acc[i][j] > bv) { bv = acc[i][j]; bj = j; }
            int row = ty * 16 + i;
            int gk = k0 + ((bj < 4) ? (tx * 4 + bj) : (128 + tx * 4 + (bj - 4)));
            sval[tx * SS + row] = bv;
            sidx[tx * SS + row] = gk;
        }
        __syncthreads();
        if (tid < 128) {
            float bv = sval[tid]; int bi = sidx[tid];
            for (int t = 1; t < 32; ++t) {
                float v = sval[t * SS + tid];
                int   x = sidx[t * SS + tid];
                if (v > bv || (v == bv && x < bi)) { bv = v; bi = x; }
            }
            if (chunk == 0 || bv > bbv || (bv == bbv && bi < bbk)) { bbv = bv; bbk = bi; }
        }
    }
    if (tid < 128) assignv[r0 + tid] = bbk;
}

__global__ __launch_bounds__(256) void update_kernel_fb(
    const float* __restrict__ E, const int* __restrict__ assignv,
    float* __restrict__ C)
{
    const int k = blockIdx.x;
    __shared__ float acc[4][DD];
    __shared__ int   cnts[4];
    __shared__ float red[4];

    const int tid  = threadIdx.x;
    const int w    = tid >> 6;
    const int lane = tid & 63;

    float a0 = 0.f, a1 = 0.f;
    int cnt = 0;
    const int base = w * (NN / 4);

    for (int it = 0; it < (NN / 4) / 256; ++it) {
        const int off = base + it * 256;
        int4 as = *(const int4*)&assignv[off + lane * 4];
        int av[4] = {as.x, as.y, as.z, as.w};
#pragma unroll
        for (int c = 0; c < 4; ++c) {
            unsigned long long m = __ballot(av[c] == k);
            cnt += (int)__popcll(m);
            while (m) {
                int b = __ffsll((long long)m) - 1; m &= m - 1;
                int r = off + b * 4 + c;
                float2 v = *(const float2*)&E[r * DD + lane * 2];
                a0 += v.x; a1 += v.y;
            }
        }
    }
    acc[w][lane * 2]     = a0;
    acc[w][lane * 2 + 1] = a1;
    if (lane == 0) cnts[w] = cnt;
    __syncthreads();

    float m = 0.f;
    const int ctot = cnts[0] + cnts[1] + cnts[2] + cnts[3];
    if (tid < DD) {
        float s = acc[0][tid] + acc[1][tid] + acc[2][tid] + acc[3][tid];
        m = (ctot > 0) ? s / (float)ctot : C[k * DD + tid];
    }
    float sq = m * m;
#pragma unroll
    for (int o = 32; o > 0; o >>= 1) sq += __shfl_down(sq, o, 64);
    if (lane == 0) red[w] = sq;
    __syncthreads();
    if (tid < DD) {
        float nrm = fmaxf(sqrtf(red[0] + red[1]), 1e-12f);
        C[k * DD + tid] = m / nrm;
    }
}

__global__ void finalize_kernel(float* __restrict__ out)
{
    int i = blockIdx.x * 256 + threadIdx.x;
    if (i < NN) {
        int a = ((const int*)out)[i];
        out[i] = (float)a;
    }
}

extern "C" void kernel_launch(void* const* d_in, const int* in_sizes, int n_in,
                              void* d_out, int out_size, void* d_ws, size_t ws_size,
                              hipStream_t stream)
{
    (void)in_sizes; (void)n_in; (void)out_size;

    const float* E  = (const float*)d_in[0];
    const float* C0 = (const float*)d_in[1];
    // num_iters (d_in[2]) is a fixed scalar = 5; hardcoded (graph-safe).

    float* out     = (float*)d_out;
    float* C       = out + NN;        // centroids in d_out tail
    int*   assignv = (int*)out;       // assign ints in d_out head

    const bool fast = (ws_size >= (size_t)WS_NEEDED);
    unsigned short* assign16 = (unsigned short*)d_ws;
    float* ws_sums = (float*)((char*)d_ws + WS_SUMS_OFF);
    int*   ws_cnts = (int*)((char*)d_ws + WS_CNTS_OFF);
    float* CTg     = (float*)((char*)d_ws + WS_CTG_OFF);
    // Every ws region is fully written each call before any read
    // (assign16 by assign_kernel, sums/cnts by update_partial, CTg by
    // transpose_c) — poison-safe.

    hipMemcpyAsync(C, C0, (size_t)KK * DD * sizeof(float),
                   hipMemcpyDeviceToDevice, stream);

    for (int it = 0; it < NITER; ++it) {
        if (fast) {
            transpose_c_kernel<<<KK * DD / 256, 256, 0, stream>>>(C, CTg);
            assign_kernel<<<NN / 128, 256, 0, stream>>>(E, CTg, assignv, assign16);
            update_partial_kernel<<<2048, 256, 0, stream>>>(E, assign16, ws_sums, ws_cnts);
            update_combine_kernel<<<KK, 128, 0, stream>>>(ws_sums, ws_cnts, C);
        } else {
            assign_kernel_fb<<<NN / 128, 256, 0, stream>>>(E, C, assignv);
            update_kernel_fb<<<KK, 256, 0, stream>>>(E, assignv, C);
        }
    }
    finalize_kernel<<<(NN + 255) / 256, 256, 0, stream>>>(out);
}